// Round 13
// baseline (189.960 us; speedup 1.0000x reference)
//
#include <hip/hip_runtime.h>
#include <hip/hip_bf16.h>

#define F 256
#define V 512
#define NB 8   // texture batch
#define NC 8   // n_code
#define NH 4
#define DQ 64
#define EPS 1e-6f
#define CEXPQ 0.18033688f   // 0.125 * log2(e), folded into Q at qkv epilogue

typedef __hip_bfloat16 bf16;
typedef __attribute__((ext_vector_type(8))) short short8;   // 8 bf16 MFMA operand
typedef __attribute__((ext_vector_type(4))) float f32x4;    // MFMA accumulator
typedef __attribute__((ext_vector_type(4))) unsigned uint4v;

__device__ __forceinline__ float b2f(bf16 x){ return __bfloat162float(x); }
__device__ __forceinline__ float shf(short s){
    return __bfloat162float(__builtin_bit_cast(bf16, (unsigned short)s));
}

#define MFMA(a,b,c) __builtin_amdgcn_mfma_f32_16x16x32_bf16((a),(b),(c),0,0,0)

__device__ __forceinline__ unsigned pack2bf(float a, float b){
    unsigned short ua = __builtin_bit_cast(unsigned short, __float2bfloat16(a));
    unsigned short ub = __builtin_bit_cast(unsigned short, __float2bfloat16(b));
    return (unsigned)ua | ((unsigned)ub << 16);
}

// ---- K0: fused weight-cast (6x 256x256 fp32 -> bf16) + LayerNorm (R5-proven, frozen).
// blocks [0,2048): LN wave-per-row; blocks [2048,2432): castw.
__global__ __launch_bounds__(256) void pre_kernel(const float* __restrict__ code,
                          const float* __restrict__ tex,
                          const float* __restrict__ ln1_g, const float* __restrict__ ln1_b,
                          const float* __restrict__ ln2_g, const float* __restrict__ ln2_b,
                          const float* __restrict__ w0, const float* __restrict__ w1,
                          const float* __restrict__ w2, const float* __restrict__ w3,
                          const float* __restrict__ w4, const float* __restrict__ w5,
                          bf16* __restrict__ cn, bf16* __restrict__ tn, bf16* __restrict__ tb,
                          bf16* __restrict__ wdst){
    if (blockIdx.x >= 2048){
        int bid = blockIdx.x - 2048;
        int which = bid >> 6;
        int idx = (((bid & 63) << 8) | threadIdx.x) << 2;
        const float* s = which==0?w0: which==1?w1: which==2?w2: which==3?w3: which==4?w4: w5;
        float4 v = *(const float4*)(s + idx);
        uint2 p; p.x = pack2bf(v.x, v.y); p.y = pack2bf(v.z, v.w);
        *(uint2*)(wdst + which * (F*F) + idx) = p;
        return;
    }
    int w = threadIdx.x >> 6, lane = threadIdx.x & 63;
    int r = blockIdx.x * 4 + w;
    int is_tex = r >> 12;
    int row = r & 4095;
    const float* src = is_tex ? tex : code;
    const float* g   = is_tex ? ln2_g : ln1_g;
    const float* be  = is_tex ? ln2_b : ln1_b;
    bf16* dst        = is_tex ? tn : cn;

    float4 x = *(const float4*)(src + row * F + lane * 4);
    if (is_tex){
        uint2 p; p.x = pack2bf(x.x, x.y); p.y = pack2bf(x.z, x.w);
        *(uint2*)(tb + row * F + lane * 4) = p;
    }
    float s = x.x + x.y + x.z + x.w;
    #pragma unroll
    for(int m = 1; m < 64; m <<= 1) s += __shfl_xor(s, m);
    float mu = s * (1.0f / F);
    float d0 = x.x - mu, d1 = x.y - mu, d2 = x.z - mu, d3 = x.w - mu;
    float q = d0*d0 + d1*d1 + d2*d2 + d3*d3;
    #pragma unroll
    for(int m = 1; m < 64; m <<= 1) q += __shfl_xor(q, m);
    float rs = rsqrtf(q * (1.0f / F) + EPS);
    float4 gg = *(const float4*)(g + lane * 4);
    float4 bb = *(const float4*)(be + lane * 4);
    uint2 p;
    p.x = pack2bf(d0 * rs * gg.x + bb.x, d1 * rs * gg.y + bb.y);
    p.y = pack2bf(d2 * rs * gg.z + bb.z, d3 * rs * gg.w + bb.w);
    *(uint2*)(dst + row * F + lane * 4) = p;
}

// ---- K1: QKV MFMA GEMM, M=4096 N=256 K=256. grid (64, 4, 3), 4 waves of 16x64. (frozen)
// z=0: Q (pre-scaled by CEXPQ) -> qn row-major; z=1: K -> k4 sigma-permuted A-frag layout
//   sigma(kt*16+i) = (i>>2)*8 + kt*4 + (i&3): QK^T output is lane-local PV B-frag.
// z=2: V -> v4 chunk-tiled.
__global__ __launch_bounds__(256)
void qkv_kernel(const bf16* __restrict__ cn,
                const bf16* __restrict__ tn,
                const bf16* __restrict__ wbf,
                const float* __restrict__ bq,
                const float* __restrict__ bk,
                const float* __restrict__ bv,
                bf16* __restrict__ qn,
                bf16* __restrict__ k4,
                bf16* __restrict__ v4){
    __shared__ bf16 ts[64][72];
    int which = blockIdx.z;
    const bf16* in   = (which == 0) ? tn : cn;
    const bf16* wb   = wbf + which * (F * F);
    const float* bias = (which == 0) ? bq : (which == 1) ? bk : bv;

    int tid = threadIdx.x;
    int w = tid >> 6, lane = tid & 63;
    int lg = lane >> 4, li = lane & 15;
    int rowbase = blockIdx.x * 64 + w * 16;
    int colbase = blockIdx.y * 64;

    f32x4 acc[4];
    #pragma unroll
    for(int ni = 0; ni < 4; ni++) acc[ni] = (f32x4){0.f,0.f,0.f,0.f};

    const bf16* arow = in + (rowbase + li) * F + lg * 8;
    const bf16* brow = wb + (colbase + li) * F + lg * 8;

    #pragma unroll
    for(int kc = 0; kc < 8; kc++){
        short8 a = *(const short8*)(arow + kc * 32);
        #pragma unroll
        for(int ni = 0; ni < 4; ni++){
            short8 bbf = *(const short8*)(brow + ni * 16 * F + kc * 32);
            acc[ni] = MFMA(a, bbf, acc[ni]);
        }
    }

    // stage (acc + bias) [* CEXPQ for Q] to LDS; V transposed [col][key_local]
    float cscale = (which == 0) ? CEXPQ : 1.0f;
    if (which < 2){
        #pragma unroll
        for(int ni = 0; ni < 4; ni++)
            #pragma unroll
            for(int r = 0; r < 4; r++)
                ts[w * 16 + lg * 4 + r][ni * 16 + li] =
                    __float2bfloat16((acc[ni][r] + bias[colbase + ni * 16 + li]) * cscale);
    } else {
        #pragma unroll
        for(int ni = 0; ni < 4; ni++)
            #pragma unroll
            for(int r = 0; r < 4; r++)
                ts[ni * 16 + li][w * 16 + lg * 4 + r] =
                    __float2bfloat16(acc[ni][r] + bias[colbase + ni * 16 + li]);
    }
    __syncthreads();

    if (which == 0){
        int rr = tid >> 2, gg2 = tid & 3;
        *(short8*)(qn + (blockIdx.x * 64 + rr) * F + colbase + gg2 * 16)
            = *(const short8*)&ts[rr][gg2 * 16];
    } else if (which == 1){
        // k4 fragment layout: fi = ((n*16+kc2)*2+kt)*8 + hh*2 + ks ; elem lgp*128+lip*8+j
        // sigma: frag (kt), A-row slot lip holds key (lip>>2)*8 + kt*4 + (lip&3)
        int n = blockIdx.x >> 3;
        int kc2base = (blockIdx.x & 7) * 2;
        int hh = blockIdx.y;
        #pragma unroll
        for(int rep = 0; rep < 2; rep++){
            int c = tid + 256 * rep;
            int f = c >> 6, wf = c & 63;
            int lgp = wf >> 4, lip = wf & 15;
            int kc2l = f >> 2, kt = (f >> 1) & 1, ks = f & 1;
            int keysel = ((lip >> 2) * 8) + kt * 4 + (lip & 3);
            int fi = ((n * 16 + kc2base + kc2l) * 2 + kt) * 8 + hh * 2 + ks;
            *(short8*)(k4 + fi * 512 + lgp * 128 + lip * 8)
                = *(const short8*)&ts[kc2l * 32 + keysel][ks * 32 + lgp * 8];
        }
    } else {
        int col = tid & 63, half = tid >> 6;
        int keybase = blockIdx.x * 64;
        int n = keybase >> 9;
        int keyl = (keybase & (V - 1)) + half * 16;
        int chunk = keyl >> 5, off = keyl & 31;
        *(short8*)(v4 + ((n * 16 + chunk) * F + colbase + col) * 32 + off)
            = *(const short8*)&ts[col][half * 16];
    }
}

// ---- K2 MEGA: flash attention + Wo + tex residual + ffln LN + W1/ReLU + W2 + residual -> out.
// grid (64, 8): x = (n = x&7 XCD swizzle, b = x>>3), y = 64-row qtile. 512 thr = 8 waves
// = (4 heads x 2 q-halves). NEW vs R8: explicit 1-chunk-ahead K/V register prefetch with
// __builtin_amdgcn_sched_barrier(0) pinning — loads for chunk kc+1 issue before chunk kc's
// compute and CANNOT be sunk past the fence (R1's failure mode). Budget: 2 blocks/CU
// (grid-limited) = 4 waves/SIMD, so VGPR <= 128 is residency-free; prefetch adds 32 VGPR.
// Compiler emits counted vmcnt (wait oldest-8, leave newest-8 in flight) automatically.
__global__ __launch_bounds__(512) void attn_mlp_kernel(const bf16* __restrict__ qn,
                                                       const bf16* __restrict__ k4,
                                                       const bf16* __restrict__ v4,
                                                       const bf16* __restrict__ wbf,
                                                       const float* __restrict__ bo,
                                                       const bf16* __restrict__ tb,
                                                       const float* __restrict__ ffg,
                                                       const float* __restrict__ ffb,
                                                       const float* __restrict__ b1,
                                                       const float* __restrict__ b2,
                                                       float* __restrict__ out){
    __shared__ bf16 xs[64][264];        // ctx -> x -> xhat -> h1 (reused)
    int n = blockIdx.x & 7, b = blockIdx.x >> 3, qt = blockIdx.y;
    int tid = threadIdx.x;
    int w = tid >> 6, lane = tid & 63;
    int h = w & 3, qh = w >> 2;
    int lg = lane >> 4, li = lane & 15;

    // Q B-frags resident: 2 q-tiles of 16
    short8 qB[2][2];
    #pragma unroll
    for(int qq = 0; qq < 2; qq++)
        #pragma unroll
        for(int ks = 0; ks < 2; ks++)
            qB[qq][ks] = *(const short8*)(qn + (b * V + qt * 64 + qh * 32 + qq * 16 + li) * F
                                             + h * DQ + ks * 32 + lg * 8);

    f32x4 o[2][4], ls[2];
    #pragma unroll
    for(int qq = 0; qq < 2; qq++){
        #pragma unroll
        for(int dt = 0; dt < 4; dt++) o[qq][dt] = (f32x4){0.f,0.f,0.f,0.f};
        ls[qq] = (f32x4){0.f,0.f,0.f,0.f};
    }

    short8 ones8;
    #pragma unroll
    for(int j = 0; j < 8; j++) ones8[j] = (short)0x3F80;   // bf16 1.0

    int fel = lg * 128 + li * 8;

    // double-buffered K/V prefetch registers; preload chunk 0 into buffer 0
    short8 kb[2][4], vb2[2][4];
    {
        int fb = ((n * 16 + 0) * 2) * 8 + h * 2;
        kb[0][0] = *(const short8*)(k4 + (fb + 0) * 512 + fel);
        kb[0][1] = *(const short8*)(k4 + (fb + 1) * 512 + fel);
        kb[0][2] = *(const short8*)(k4 + (fb + 8) * 512 + fel);
        kb[0][3] = *(const short8*)(k4 + (fb + 9) * 512 + fel);
        const bf16* vbp = v4 + ((n * 16 + 0) * F + h * DQ) * 32;
        vb2[0][0] = *(const short8*)(vbp + (0 * 16 + li) * 32 + lg * 8);
        vb2[0][1] = *(const short8*)(vbp + (1 * 16 + li) * 32 + lg * 8);
        vb2[0][2] = *(const short8*)(vbp + (2 * 16 + li) * 32 + lg * 8);
        vb2[0][3] = *(const short8*)(vbp + (3 * 16 + li) * 32 + lg * 8);
    }

    #pragma unroll
    for(int kc = 0; kc < 16; kc++){
        const int cur = kc & 1, nxt = cur ^ 1;
        // issue chunk kc+1 loads; the fence below keeps them ABOVE chunk kc's compute
        if (kc < 15){
            int fb = ((n * 16 + kc + 1) * 2) * 8 + h * 2;
            kb[nxt][0] = *(const short8*)(k4 + (fb + 0) * 512 + fel);
            kb[nxt][1] = *(const short8*)(k4 + (fb + 1) * 512 + fel);
            kb[nxt][2] = *(const short8*)(k4 + (fb + 8) * 512 + fel);
            kb[nxt][3] = *(const short8*)(k4 + (fb + 9) * 512 + fel);
            const bf16* vbp = v4 + ((n * 16 + kc + 1) * F + h * DQ) * 32;
            vb2[nxt][0] = *(const short8*)(vbp + (0 * 16 + li) * 32 + lg * 8);
            vb2[nxt][1] = *(const short8*)(vbp + (1 * 16 + li) * 32 + lg * 8);
            vb2[nxt][2] = *(const short8*)(vbp + (2 * 16 + li) * 32 + lg * 8);
            vb2[nxt][3] = *(const short8*)(vbp + (3 * 16 + li) * 32 + lg * 8);
        }
        __builtin_amdgcn_sched_barrier(0);   // prefetch may not sink below this point

        #pragma unroll
        for(int qq = 0; qq < 2; qq++){
            f32x4 st0 = (f32x4){0.f,0.f,0.f,0.f};
            f32x4 st1 = (f32x4){0.f,0.f,0.f,0.f};
            __builtin_amdgcn_s_setprio(1);
            st0 = MFMA(kb[cur][0], qB[qq][0], st0);
            st1 = MFMA(kb[cur][2], qB[qq][0], st1);
            st0 = MFMA(kb[cur][1], qB[qq][1], st0);
            st1 = MFMA(kb[cur][3], qB[qq][1], st1);
            __builtin_amdgcn_s_setprio(0);

            // Q pre-scaled: p = exp2(st). sigma rows: st0[r]=P[key lg*8+r], st1[r]=P[key lg*8+4+r]
            float p0[4], p1[4];
            #pragma unroll
            for(int r = 0; r < 4; r++){
                p0[r] = exp2f(st0[r]);
                p1[r] = exp2f(st1[r]);
            }

            uint4v uv;
            uv.x = pack2bf(p0[0], p0[1]);
            uv.y = pack2bf(p0[2], p0[3]);
            uv.z = pack2bf(p1[0], p1[1]);
            uv.w = pack2bf(p1[2], p1[3]);
            short8 pfrag = __builtin_bit_cast(short8, uv);

            __builtin_amdgcn_s_setprio(1);
            o[qq][0] = MFMA(vb2[cur][0], pfrag, o[qq][0]);
            o[qq][1] = MFMA(vb2[cur][1], pfrag, o[qq][1]);
            o[qq][2] = MFMA(vb2[cur][2], pfrag, o[qq][2]);
            o[qq][3] = MFMA(vb2[cur][3], pfrag, o[qq][3]);
            ls[qq] = MFMA(ones8, pfrag, ls[qq]);   // l = sum_k P, lane-complete
            __builtin_amdgcn_s_setprio(0);
        }
    }

    float inv[2];
    #pragma unroll
    for(int qq = 0; qq < 2; qq++) inv[qq] = 1.0f / ls[qq][0];

    // stage normalized O to LDS as ctx[qrel][col]
    #pragma unroll
    for(int qq = 0; qq < 2; qq++)
        #pragma unroll
        for(int dt = 0; dt < 4; dt++){
            uint2 pkd;
            pkd.x = pack2bf(o[qq][dt][0] * inv[qq], o[qq][dt][1] * inv[qq]);
            pkd.y = pack2bf(o[qq][dt][2] * inv[qq], o[qq][dt][3] * inv[qq]);
            *(uint2*)&xs[qh * 32 + qq * 16 + li][h * DQ + dt * 16 + lg * 4] = pkd;
        }
    __syncthreads();

    // ---- Wo GEMM + bo + tex residual -> xres (registers, fp32). 64 rows x 32 wave-cols.
    const bf16* Wo = wbf + 3 * (F * F);
    int colbase = w * 32;
    f32x4 xac[4][2];
    #pragma unroll
    for(int mi = 0; mi < 4; mi++)
        #pragma unroll
        for(int ni = 0; ni < 2; ni++) xac[mi][ni] = (f32x4){0.f,0.f,0.f,0.f};
    #pragma unroll
    for(int kc = 0; kc < 8; kc++){
        short8 a[4];
        #pragma unroll
        for(int mi = 0; mi < 4; mi++)
            a[mi] = *(const short8*)&xs[mi * 16 + li][kc * 32 + lg * 8];
        #pragma unroll
        for(int ni = 0; ni < 2; ni++){
            short8 bw = *(const short8*)(Wo + (colbase + ni * 16 + li) * F + kc * 32 + lg * 8);
            #pragma unroll
            for(int mi = 0; mi < 4; mi++)
                xac[mi][ni] = MFMA(a[mi], bw, xac[mi][ni]);
        }
    }
    float xres[4][2][4];
    #pragma unroll
    for(int mi = 0; mi < 4; mi++)
        #pragma unroll
        for(int r = 0; r < 4; r++){
            int qrel = mi * 16 + lg * 4 + r;
            #pragma unroll
            for(int ni = 0; ni < 2; ni++){
                int col = colbase + ni * 16 + li;
                xres[mi][ni][r] = xac[mi][ni][r] + bo[col]
                                + b2f(tb[(b * V + qt * 64 + qrel) * F + col]);
            }
        }
    __syncthreads();                  // all ctx reads done
    // write x (bf16) into xs
    #pragma unroll
    for(int mi = 0; mi < 4; mi++)
        #pragma unroll
        for(int r = 0; r < 4; r++){
            int qrel = mi * 16 + lg * 4 + r;
            #pragma unroll
            for(int ni = 0; ni < 2; ni++)
                xs[qrel][colbase + ni * 16 + li] = __float2bfloat16(xres[mi][ni][r]);
        }
    __syncthreads();

    // ---- ffln LN: 8 threads per row (64 rows), one-pass, 8-lane shuffle reduce
    int row = tid >> 3, sub = tid & 7;
    short8 xv[4];
    #pragma unroll
    for(int seg = 0; seg < 4; seg++)
        xv[seg] = *(const short8*)&xs[row][sub * 32 + seg * 8];
    float sum = 0.f, sq = 0.f;
    #pragma unroll
    for(int seg = 0; seg < 4; seg++)
        #pragma unroll
        for(int j = 0; j < 8; j++){
            float v0 = shf(xv[seg][j]);
            sum += v0; sq += v0 * v0;
        }
    #pragma unroll
    for(int m = 1; m < 8; m <<= 1){
        sum += __shfl_xor(sum, m);
        sq  += __shfl_xor(sq, m);
    }
    float mu = sum * (1.0f / F);
    float var = sq * (1.0f / F) - mu * mu;
    float rsv = rsqrtf(var + EPS);
    #pragma unroll
    for(int seg = 0; seg < 4; seg++){
        int c = sub * 32 + seg * 8;
        float4 g0 = *(const float4*)(ffg + c);
        float4 g1 = *(const float4*)(ffg + c + 4);
        float4 f0 = *(const float4*)(ffb + c);
        float4 f1 = *(const float4*)(ffb + c + 4);
        float n0 = (shf(xv[seg][0]) - mu) * rsv * g0.x + f0.x;
        float n1 = (shf(xv[seg][1]) - mu) * rsv * g0.y + f0.y;
        float n2 = (shf(xv[seg][2]) - mu) * rsv * g0.z + f0.z;
        float n3 = (shf(xv[seg][3]) - mu) * rsv * g0.w + f0.w;
        float n4 = (shf(xv[seg][4]) - mu) * rsv * g1.x + f1.x;
        float n5 = (shf(xv[seg][5]) - mu) * rsv * g1.y + f1.y;
        float n6 = (shf(xv[seg][6]) - mu) * rsv * g1.z + f1.z;
        float n7 = (shf(xv[seg][7]) - mu) * rsv * g1.w + f1.w;
        uint4v pk;
        pk.x = pack2bf(n0, n1); pk.y = pack2bf(n2, n3);
        pk.z = pack2bf(n4, n5); pk.w = pack2bf(n6, n7);
        *(short8*)&xs[row][c] = __builtin_bit_cast(short8, pk);
    }
    __syncthreads();

    // ---- GEMM1: h = relu(xhat @ W1^T + b1), 64 rows x 32 wave-cols
    const bf16* W1b = wbf + 4 * (F * F);
    f32x4 hac[4][2];
    #pragma unroll
    for(int mi = 0; mi < 4; mi++)
        #pragma unroll
        for(int ni = 0; ni < 2; ni++) hac[mi][ni] = (f32x4){0.f,0.f,0.f,0.f};
    #pragma unroll
    for(int kc = 0; kc < 8; kc++){
        short8 a[4];
        #pragma unroll
        for(int mi = 0; mi < 4; mi++)
            a[mi] = *(const short8*)&xs[mi * 16 + li][kc * 32 + lg * 8];
        #pragma unroll
        for(int ni = 0; ni < 2; ni++){
            short8 bw = *(const short8*)(W1b + (colbase + ni * 16 + li) * F + kc * 32 + lg * 8);
            #pragma unroll
            for(int mi = 0; mi < 4; mi++)
                hac[mi][ni] = MFMA(a[mi], bw, hac[mi][ni]);
        }
    }
    __syncthreads();                  // xhat reads done
    #pragma unroll
    for(int mi = 0; mi < 4; mi++)
        #pragma unroll
        for(int r = 0; r < 4; r++){
            int rr = mi * 16 + lg * 4 + r;
            #pragma unroll
            for(int ni = 0; ni < 2; ni++){
                int col = colbase + ni * 16 + li;
                xs[rr][col] = __float2bfloat16(fmaxf(hac[mi][ni][r] + b1[col], 0.f));
            }
        }
    __syncthreads();

    // ---- GEMM2: out = x + h @ W2^T + b2
    const bf16* W2b = wbf + 5 * (F * F);
    f32x4 oac[4][2];
    #pragma unroll
    for(int mi = 0; mi < 4; mi++)
        #pragma unroll
        for(int ni = 0; ni < 2; ni++) oac[mi][ni] = (f32x4){0.f,0.f,0.f,0.f};
    #pragma unroll
    for(int kc = 0; kc < 8; kc++){
        short8 a[4];
        #pragma unroll
        for(int mi = 0; mi < 4; mi++)
            a[mi] = *(const short8*)&xs[mi * 16 + li][kc * 32 + lg * 8];
        #pragma unroll
        for(int ni = 0; ni < 2; ni++){
            short8 bw = *(const short8*)(W2b + (colbase + ni * 16 + li) * F + kc * 32 + lg * 8);
            #pragma unroll
            for(int mi = 0; mi < 4; mi++)
                oac[mi][ni] = MFMA(a[mi], bw, oac[mi][ni]);
        }
    }
    #pragma unroll
    for(int mi = 0; mi < 4; mi++)
        #pragma unroll
        for(int r = 0; r < 4; r++){
            int qrel = mi * 16 + lg * 4 + r;
            int ro = (b * NC + n) * V + qt * 64 + qrel;
            #pragma unroll
            for(int ni = 0; ni < 2; ni++){
                int col = colbase + ni * 16 + li;
                out[ro * F + col] = oac[mi][ni][r] + b2[col] + xres[mi][ni][r];
            }
        }
}

extern "C" void kernel_launch(void* const* d_in, const int* in_sizes, int n_in,
                              void* d_out, int out_size, void* d_ws, size_t ws_size,
                              hipStream_t stream) {
    const float* code_map = (const float*)d_in[0];
    const float* tex_map  = (const float*)d_in[1];
    const float* Wq = (const float*)d_in[2];  const float* bq = (const float*)d_in[3];
    const float* Wk = (const float*)d_in[4];  const float* bk = (const float*)d_in[5];
    const float* Wv = (const float*)d_in[6];  const float* bv = (const float*)d_in[7];
    const float* Wo = (const float*)d_in[8];  const float* bo = (const float*)d_in[9];
    const float* ln1_g = (const float*)d_in[10]; const float* ln1_b = (const float*)d_in[11];
    const float* ln2_g = (const float*)d_in[12]; const float* ln2_b = (const float*)d_in[13];
    const float* ffln_g = (const float*)d_in[14]; const float* ffln_b = (const float*)d_in[15];
    const float* W1 = (const float*)d_in[16]; const float* b1 = (const float*)d_in[17];
    const float* W2 = (const float*)d_in[18]; const float* b2 = (const float*)d_in[19];
    float* out = (float*)d_out;

    // ws layout (bf16 elements)
    bf16* ws  = (bf16*)d_ws;
    bf16* qn  = ws;                       // 4096*256 = 1048576 (pre-scaled Q)
    bf16* k4  = qn + 1048576;             // 1048576 (A-frag layout, sigma-permuted keys)
    bf16* v4  = k4 + 1048576;             // 1048576 (chunk-tiled V)
    bf16* cn  = v4 + 1048576;             // 1048576
    bf16* tn  = cn + 1048576;             // 1048576
    bf16* tb  = tn + 1048576;             // 1048576 (bf16 texture copy)
    bf16* wbf = tb + 1048576;             // 6*256*256 = 393216 (Wq,Wk,Wv,Wo,W1,W2)

    pre_kernel<<<2048 + 384, 256, 0, stream>>>(code_map, tex_map, ln1_g, ln1_b, ln2_g, ln2_b,
                                               Wq, Wk, Wv, Wo, W1, W2, cn, tn, tb, wbf);
    qkv_kernel<<<dim3(64, 4, 3), 256, 0, stream>>>(cn, tn, wbf, bq, bk, bv, qn, k4, v4);
    attn_mlp_kernel<<<dim3(64, 8), 512, 0, stream>>>(qn, k4, v4, wbf, bo, tb,
                                                     ffln_g, ffln_b, b1, b2, out);
}

// Round 14
// 182.724 us; speedup vs baseline: 1.0396x; 1.0396x over previous
//
#include <hip/hip_runtime.h>
#include <hip/hip_bf16.h>

#define F 256
#define V 512
#define NB 8   // texture batch
#define NC 8   // n_code
#define NH 4
#define DQ 64
#define EPS 1e-6f
#define CEXPQ 0.18033688f   // 0.125 * log2(e), folded into Q at qkv epilogue

typedef __hip_bfloat16 bf16;
typedef __attribute__((ext_vector_type(8))) short short8;   // 8 bf16 MFMA operand
typedef __attribute__((ext_vector_type(4))) float f32x4;    // MFMA accumulator
typedef __attribute__((ext_vector_type(4))) unsigned uint4v;

__device__ __forceinline__ float b2f(bf16 x){ return __bfloat162float(x); }
__device__ __forceinline__ float shf(short s){
    return __bfloat162float(__builtin_bit_cast(bf16, (unsigned short)s));
}

#define MFMA(a,b,c) __builtin_amdgcn_mfma_f32_16x16x32_bf16((a),(b),(c),0,0,0)

__device__ __forceinline__ unsigned pack2bf(float a, float b){
    unsigned short ua = __builtin_bit_cast(unsigned short, __float2bfloat16(a));
    unsigned short ub = __builtin_bit_cast(unsigned short, __float2bfloat16(b));
    return (unsigned)ua | ((unsigned)ub << 16);
}

// ---- K0: fused weight-cast (6x 256x256 fp32 -> bf16) + LayerNorm (R5-proven, frozen).
// blocks [0,2048): LN wave-per-row; blocks [2048,2432): castw.
__global__ __launch_bounds__(256) void pre_kernel(const float* __restrict__ code,
                          const float* __restrict__ tex,
                          const float* __restrict__ ln1_g, const float* __restrict__ ln1_b,
                          const float* __restrict__ ln2_g, const float* __restrict__ ln2_b,
                          const float* __restrict__ w0, const float* __restrict__ w1,
                          const float* __restrict__ w2, const float* __restrict__ w3,
                          const float* __restrict__ w4, const float* __restrict__ w5,
                          bf16* __restrict__ cn, bf16* __restrict__ tn, bf16* __restrict__ tb,
                          bf16* __restrict__ wdst){
    if (blockIdx.x >= 2048){
        int bid = blockIdx.x - 2048;
        int which = bid >> 6;
        int idx = (((bid & 63) << 8) | threadIdx.x) << 2;
        const float* s = which==0?w0: which==1?w1: which==2?w2: which==3?w3: which==4?w4: w5;
        float4 v = *(const float4*)(s + idx);
        uint2 p; p.x = pack2bf(v.x, v.y); p.y = pack2bf(v.z, v.w);
        *(uint2*)(wdst + which * (F*F) + idx) = p;
        return;
    }
    int w = threadIdx.x >> 6, lane = threadIdx.x & 63;
    int r = blockIdx.x * 4 + w;
    int is_tex = r >> 12;
    int row = r & 4095;
    const float* src = is_tex ? tex : code;
    const float* g   = is_tex ? ln2_g : ln1_g;
    const float* be  = is_tex ? ln2_b : ln1_b;
    bf16* dst        = is_tex ? tn : cn;

    float4 x = *(const float4*)(src + row * F + lane * 4);
    if (is_tex){
        uint2 p; p.x = pack2bf(x.x, x.y); p.y = pack2bf(x.z, x.w);
        *(uint2*)(tb + row * F + lane * 4) = p;
    }
    float s = x.x + x.y + x.z + x.w;
    #pragma unroll
    for(int m = 1; m < 64; m <<= 1) s += __shfl_xor(s, m);
    float mu = s * (1.0f / F);
    float d0 = x.x - mu, d1 = x.y - mu, d2 = x.z - mu, d3 = x.w - mu;
    float q = d0*d0 + d1*d1 + d2*d2 + d3*d3;
    #pragma unroll
    for(int m = 1; m < 64; m <<= 1) q += __shfl_xor(q, m);
    float rs = rsqrtf(q * (1.0f / F) + EPS);
    float4 gg = *(const float4*)(g + lane * 4);
    float4 bb = *(const float4*)(be + lane * 4);
    uint2 p;
    p.x = pack2bf(d0 * rs * gg.x + bb.x, d1 * rs * gg.y + bb.y);
    p.y = pack2bf(d2 * rs * gg.z + bb.z, d3 * rs * gg.w + bb.w);
    *(uint2*)(dst + row * F + lane * 4) = p;
}

// ---- K1: QKV MFMA GEMM, M=4096 N=256 K=256. grid (64, 4, 3), 4 waves of 16x64. (frozen)
// z=0: Q (pre-scaled by CEXPQ) -> qn row-major; z=1: K -> k4 sigma-permuted A-frag layout
//   sigma(kt*16+i) = (i>>2)*8 + kt*4 + (i&3): QK^T output is lane-local PV B-frag.
// z=2: V -> v4 chunk-tiled.
__global__ __launch_bounds__(256)
void qkv_kernel(const bf16* __restrict__ cn,
                const bf16* __restrict__ tn,
                const bf16* __restrict__ wbf,
                const float* __restrict__ bq,
                const float* __restrict__ bk,
                const float* __restrict__ bv,
                bf16* __restrict__ qn,
                bf16* __restrict__ k4,
                bf16* __restrict__ v4){
    __shared__ bf16 ts[64][72];
    int which = blockIdx.z;
    const bf16* in   = (which == 0) ? tn : cn;
    const bf16* wb   = wbf + which * (F * F);
    const float* bias = (which == 0) ? bq : (which == 1) ? bk : bv;

    int tid = threadIdx.x;
    int w = tid >> 6, lane = tid & 63;
    int lg = lane >> 4, li = lane & 15;
    int rowbase = blockIdx.x * 64 + w * 16;
    int colbase = blockIdx.y * 64;

    f32x4 acc[4];
    #pragma unroll
    for(int ni = 0; ni < 4; ni++) acc[ni] = (f32x4){0.f,0.f,0.f,0.f};

    const bf16* arow = in + (rowbase + li) * F + lg * 8;
    const bf16* brow = wb + (colbase + li) * F + lg * 8;

    #pragma unroll
    for(int kc = 0; kc < 8; kc++){
        short8 a = *(const short8*)(arow + kc * 32);
        #pragma unroll
        for(int ni = 0; ni < 4; ni++){
            short8 bbf = *(const short8*)(brow + ni * 16 * F + kc * 32);
            acc[ni] = MFMA(a, bbf, acc[ni]);
        }
    }

    // stage (acc + bias) [* CEXPQ for Q] to LDS; V transposed [col][key_local]
    float cscale = (which == 0) ? CEXPQ : 1.0f;
    if (which < 2){
        #pragma unroll
        for(int ni = 0; ni < 4; ni++)
            #pragma unroll
            for(int r = 0; r < 4; r++)
                ts[w * 16 + lg * 4 + r][ni * 16 + li] =
                    __float2bfloat16((acc[ni][r] + bias[colbase + ni * 16 + li]) * cscale);
    } else {
        #pragma unroll
        for(int ni = 0; ni < 4; ni++)
            #pragma unroll
            for(int r = 0; r < 4; r++)
                ts[ni * 16 + li][w * 16 + lg * 4 + r] =
                    __float2bfloat16(acc[ni][r] + bias[colbase + ni * 16 + li]);
    }
    __syncthreads();

    if (which == 0){
        int rr = tid >> 2, gg2 = tid & 3;
        *(short8*)(qn + (blockIdx.x * 64 + rr) * F + colbase + gg2 * 16)
            = *(const short8*)&ts[rr][gg2 * 16];
    } else if (which == 1){
        // k4 fragment layout: fi = ((n*16+kc2)*2+kt)*8 + hh*2 + ks ; elem lgp*128+lip*8+j
        // sigma: frag (kt), A-row slot lip holds key (lip>>2)*8 + kt*4 + (lip&3)
        int n = blockIdx.x >> 3;
        int kc2base = (blockIdx.x & 7) * 2;
        int hh = blockIdx.y;
        #pragma unroll
        for(int rep = 0; rep < 2; rep++){
            int c = tid + 256 * rep;
            int f = c >> 6, wf = c & 63;
            int lgp = wf >> 4, lip = wf & 15;
            int kc2l = f >> 2, kt = (f >> 1) & 1, ks = f & 1;
            int keysel = ((lip >> 2) * 8) + kt * 4 + (lip & 3);
            int fi = ((n * 16 + kc2base + kc2l) * 2 + kt) * 8 + hh * 2 + ks;
            *(short8*)(k4 + fi * 512 + lgp * 128 + lip * 8)
                = *(const short8*)&ts[kc2l * 32 + keysel][ks * 32 + lgp * 8];
        }
    } else {
        int col = tid & 63, half = tid >> 6;
        int keybase = blockIdx.x * 64;
        int n = keybase >> 9;
        int keyl = (keybase & (V - 1)) + half * 16;
        int chunk = keyl >> 5, off = keyl & 31;
        *(short8*)(v4 + ((n * 16 + chunk) * F + colbase + col) * 32 + off)
            = *(const short8*)&ts[col][half * 16];
    }
}

// ---- K2 MEGA (R8/R12-proven best, 70.5us): flash attention + Wo + tex residual + ffln LN +
// W1/ReLU + W2 + residual -> out. grid (64, 8): x = (n = x&7 XCD swizzle, b = x>>3),
// y = 64-row qtile. 512 thr = 8 waves = (4 heads x 2 q-halves). Q pre-scaled (exp2 direct);
// l via ones-column MFMA (lane-complete); sigma-permuted k4 -> P lane-local for PV.
// Latency-hiding campaign verdict (R1/R7/R10/R11/R13, all measured): reg-prefetch sinks
// without a fence and serializes with one; smaller blocks double weight traffic; 64KB LDS
// staging halves residency; 16-wave blocks spill; fence drops occupancy. This design point
// -- 64 VGPR, 33KB LDS, zero flash-loop barriers, compiler-scheduled -- is the optimum.
__global__ __launch_bounds__(512) void attn_mlp_kernel(const bf16* __restrict__ qn,
                                                       const bf16* __restrict__ k4,
                                                       const bf16* __restrict__ v4,
                                                       const bf16* __restrict__ wbf,
                                                       const float* __restrict__ bo,
                                                       const bf16* __restrict__ tb,
                                                       const float* __restrict__ ffg,
                                                       const float* __restrict__ ffb,
                                                       const float* __restrict__ b1,
                                                       const float* __restrict__ b2,
                                                       float* __restrict__ out){
    __shared__ bf16 xs[64][264];        // ctx -> x -> xhat -> h1 (reused)
    int n = blockIdx.x & 7, b = blockIdx.x >> 3, qt = blockIdx.y;
    int tid = threadIdx.x;
    int w = tid >> 6, lane = tid & 63;
    int h = w & 3, qh = w >> 2;
    int lg = lane >> 4, li = lane & 15;

    // Q B-frags resident: 2 q-tiles of 16
    short8 qB[2][2];
    #pragma unroll
    for(int qq = 0; qq < 2; qq++)
        #pragma unroll
        for(int ks = 0; ks < 2; ks++)
            qB[qq][ks] = *(const short8*)(qn + (b * V + qt * 64 + qh * 32 + qq * 16 + li) * F
                                             + h * DQ + ks * 32 + lg * 8);

    f32x4 o[2][4], ls[2];
    #pragma unroll
    for(int qq = 0; qq < 2; qq++){
        #pragma unroll
        for(int dt = 0; dt < 4; dt++) o[qq][dt] = (f32x4){0.f,0.f,0.f,0.f};
        ls[qq] = (f32x4){0.f,0.f,0.f,0.f};
    }

    short8 ones8;
    #pragma unroll
    for(int j = 0; j < 8; j++) ones8[j] = (short)0x3F80;   // bf16 1.0

    int fel = lg * 128 + li * 8;

    #pragma unroll
    for(int kc = 0; kc < 16; kc++){
        int fb = ((n * 16 + kc) * 2) * 8 + h * 2;
        short8 kA0 = *(const short8*)(k4 + (fb + 0) * 512 + fel);
        short8 kA1 = *(const short8*)(k4 + (fb + 1) * 512 + fel);
        short8 kA2 = *(const short8*)(k4 + (fb + 8) * 512 + fel);
        short8 kA3 = *(const short8*)(k4 + (fb + 9) * 512 + fel);
        const bf16* vb = v4 + ((n * 16 + kc) * F + h * DQ) * 32;
        short8 vA0 = *(const short8*)(vb + (0 * 16 + li) * 32 + lg * 8);
        short8 vA1 = *(const short8*)(vb + (1 * 16 + li) * 32 + lg * 8);
        short8 vA2 = *(const short8*)(vb + (2 * 16 + li) * 32 + lg * 8);
        short8 vA3 = *(const short8*)(vb + (3 * 16 + li) * 32 + lg * 8);

        #pragma unroll
        for(int qq = 0; qq < 2; qq++){
            f32x4 st0 = (f32x4){0.f,0.f,0.f,0.f};
            f32x4 st1 = (f32x4){0.f,0.f,0.f,0.f};
            __builtin_amdgcn_s_setprio(1);
            st0 = MFMA(kA0, qB[qq][0], st0);
            st1 = MFMA(kA2, qB[qq][0], st1);
            st0 = MFMA(kA1, qB[qq][1], st0);
            st1 = MFMA(kA3, qB[qq][1], st1);
            __builtin_amdgcn_s_setprio(0);

            // Q pre-scaled: p = exp2(st). sigma rows: st0[r]=P[key lg*8+r], st1[r]=P[key lg*8+4+r]
            float p0[4], p1[4];
            #pragma unroll
            for(int r = 0; r < 4; r++){
                p0[r] = exp2f(st0[r]);
                p1[r] = exp2f(st1[r]);
            }

            uint4v uv;
            uv.x = pack2bf(p0[0], p0[1]);
            uv.y = pack2bf(p0[2], p0[3]);
            uv.z = pack2bf(p1[0], p1[1]);
            uv.w = pack2bf(p1[2], p1[3]);
            short8 pfrag = __builtin_bit_cast(short8, uv);

            __builtin_amdgcn_s_setprio(1);
            o[qq][0] = MFMA(vA0, pfrag, o[qq][0]);
            o[qq][1] = MFMA(vA1, pfrag, o[qq][1]);
            o[qq][2] = MFMA(vA2, pfrag, o[qq][2]);
            o[qq][3] = MFMA(vA3, pfrag, o[qq][3]);
            ls[qq] = MFMA(ones8, pfrag, ls[qq]);   // l = sum_k P, lane-complete
            __builtin_amdgcn_s_setprio(0);
        }
    }

    float inv[2];
    #pragma unroll
    for(int qq = 0; qq < 2; qq++) inv[qq] = 1.0f / ls[qq][0];

    // stage normalized O to LDS as ctx[qrel][col]
    #pragma unroll
    for(int qq = 0; qq < 2; qq++)
        #pragma unroll
        for(int dt = 0; dt < 4; dt++){
            uint2 pkd;
            pkd.x = pack2bf(o[qq][dt][0] * inv[qq], o[qq][dt][1] * inv[qq]);
            pkd.y = pack2bf(o[qq][dt][2] * inv[qq], o[qq][dt][3] * inv[qq]);
            *(uint2*)&xs[qh * 32 + qq * 16 + li][h * DQ + dt * 16 + lg * 4] = pkd;
        }
    __syncthreads();

    // ---- Wo GEMM + bo + tex residual -> xres (registers, fp32). 64 rows x 32 wave-cols.
    const bf16* Wo = wbf + 3 * (F * F);
    int colbase = w * 32;
    f32x4 xac[4][2];
    #pragma unroll
    for(int mi = 0; mi < 4; mi++)
        #pragma unroll
        for(int ni = 0; ni < 2; ni++) xac[mi][ni] = (f32x4){0.f,0.f,0.f,0.f};
    #pragma unroll
    for(int kc = 0; kc < 8; kc++){
        short8 a[4];
        #pragma unroll
        for(int mi = 0; mi < 4; mi++)
            a[mi] = *(const short8*)&xs[mi * 16 + li][kc * 32 + lg * 8];
        #pragma unroll
        for(int ni = 0; ni < 2; ni++){
            short8 bw = *(const short8*)(Wo + (colbase + ni * 16 + li) * F + kc * 32 + lg * 8);
            #pragma unroll
            for(int mi = 0; mi < 4; mi++)
                xac[mi][ni] = MFMA(a[mi], bw, xac[mi][ni]);
        }
    }
    float xres[4][2][4];
    #pragma unroll
    for(int mi = 0; mi < 4; mi++)
        #pragma unroll
        for(int r = 0; r < 4; r++){
            int qrel = mi * 16 + lg * 4 + r;
            #pragma unroll
            for(int ni = 0; ni < 2; ni++){
                int col = colbase + ni * 16 + li;
                xres[mi][ni][r] = xac[mi][ni][r] + bo[col]
                                + b2f(tb[(b * V + qt * 64 + qrel) * F + col]);
            }
        }
    __syncthreads();                  // all ctx reads done
    // write x (bf16) into xs
    #pragma unroll
    for(int mi = 0; mi < 4; mi++)
        #pragma unroll
        for(int r = 0; r < 4; r++){
            int qrel = mi * 16 + lg * 4 + r;
            #pragma unroll
            for(int ni = 0; ni < 2; ni++)
                xs[qrel][colbase + ni * 16 + li] = __float2bfloat16(xres[mi][ni][r]);
        }
    __syncthreads();

    // ---- ffln LN: 8 threads per row (64 rows), one-pass, 8-lane shuffle reduce
    int row = tid >> 3, sub = tid & 7;
    short8 xv[4];
    #pragma unroll
    for(int seg = 0; seg < 4; seg++)
        xv[seg] = *(const short8*)&xs[row][sub * 32 + seg * 8];
    float sum = 0.f, sq = 0.f;
    #pragma unroll
    for(int seg = 0; seg < 4; seg++)
        #pragma unroll
        for(int j = 0; j < 8; j++){
            float v0 = shf(xv[seg][j]);
            sum += v0; sq += v0 * v0;
        }
    #pragma unroll
    for(int m = 1; m < 8; m <<= 1){
        sum += __shfl_xor(sum, m);
        sq  += __shfl_xor(sq, m);
    }
    float mu = sum * (1.0f / F);
    float var = sq * (1.0f / F) - mu * mu;
    float rsv = rsqrtf(var + EPS);
    #pragma unroll
    for(int seg = 0; seg < 4; seg++){
        int c = sub * 32 + seg * 8;
        float4 g0 = *(const float4*)(ffg + c);
        float4 g1 = *(const float4*)(ffg + c + 4);
        float4 f0 = *(const float4*)(ffb + c);
        float4 f1 = *(const float4*)(ffb + c + 4);
        float n0 = (shf(xv[seg][0]) - mu) * rsv * g0.x + f0.x;
        float n1 = (shf(xv[seg][1]) - mu) * rsv * g0.y + f0.y;
        float n2 = (shf(xv[seg][2]) - mu) * rsv * g0.z + f0.z;
        float n3 = (shf(xv[seg][3]) - mu) * rsv * g0.w + f0.w;
        float n4 = (shf(xv[seg][4]) - mu) * rsv * g1.x + f1.x;
        float n5 = (shf(xv[seg][5]) - mu) * rsv * g1.y + f1.y;
        float n6 = (shf(xv[seg][6]) - mu) * rsv * g1.z + f1.z;
        float n7 = (shf(xv[seg][7]) - mu) * rsv * g1.w + f1.w;
        uint4v pk;
        pk.x = pack2bf(n0, n1); pk.y = pack2bf(n2, n3);
        pk.z = pack2bf(n4, n5); pk.w = pack2bf(n6, n7);
        *(short8*)&xs[row][c] = __builtin_bit_cast(short8, pk);
    }
    __syncthreads();

    // ---- GEMM1: h = relu(xhat @ W1^T + b1), 64 rows x 32 wave-cols
    const bf16* W1b = wbf + 4 * (F * F);
    f32x4 hac[4][2];
    #pragma unroll
    for(int mi = 0; mi < 4; mi++)
        #pragma unroll
        for(int ni = 0; ni < 2; ni++) hac[mi][ni] = (f32x4){0.f,0.f,0.f,0.f};
    #pragma unroll
    for(int kc = 0; kc < 8; kc++){
        short8 a[4];
        #pragma unroll
        for(int mi = 0; mi < 4; mi++)
            a[mi] = *(const short8*)&xs[mi * 16 + li][kc * 32 + lg * 8];
        #pragma unroll
        for(int ni = 0; ni < 2; ni++){
            short8 bw = *(const short8*)(W1b + (colbase + ni * 16 + li) * F + kc * 32 + lg * 8);
            #pragma unroll
            for(int mi = 0; mi < 4; mi++)
                hac[mi][ni] = MFMA(a[mi], bw, hac[mi][ni]);
        }
    }
    __syncthreads();                  // xhat reads done
    #pragma unroll
    for(int mi = 0; mi < 4; mi++)
        #pragma unroll
        for(int r = 0; r < 4; r++){
            int rr = mi * 16 + lg * 4 + r;
            #pragma unroll
            for(int ni = 0; ni < 2; ni++){
                int col = colbase + ni * 16 + li;
                xs[rr][col] = __float2bfloat16(fmaxf(hac[mi][ni][r] + b1[col], 0.f));
            }
        }
    __syncthreads();

    // ---- GEMM2: out = x + h @ W2^T + b2
    const bf16* W2b = wbf + 5 * (F * F);
    f32x4 oac[4][2];
    #pragma unroll
    for(int mi = 0; mi < 4; mi++)
        #pragma unroll
        for(int ni = 0; ni < 2; ni++) oac[mi][ni] = (f32x4){0.f,0.f,0.f,0.f};
    #pragma unroll
    for(int kc = 0; kc < 8; kc++){
        short8 a[4];
        #pragma unroll
        for(int mi = 0; mi < 4; mi++)
            a[mi] = *(const short8*)&xs[mi * 16 + li][kc * 32 + lg * 8];
        #pragma unroll
        for(int ni = 0; ni < 2; ni++){
            short8 bw = *(const short8*)(W2b + (colbase + ni * 16 + li) * F + kc * 32 + lg * 8);
            #pragma unroll
            for(int mi = 0; mi < 4; mi++)
                oac[mi][ni] = MFMA(a[mi], bw, oac[mi][ni]);
        }
    }
    #pragma unroll
    for(int mi = 0; mi < 4; mi++)
        #pragma unroll
        for(int r = 0; r < 4; r++){
            int qrel = mi * 16 + lg * 4 + r;
            int ro = (b * NC + n) * V + qt * 64 + qrel;
            #pragma unroll
            for(int ni = 0; ni < 2; ni++){
                int col = colbase + ni * 16 + li;
                out[ro * F + col] = oac[mi][ni][r] + b2[col] + xres[mi][ni][r];
            }
        }
}

extern "C" void kernel_launch(void* const* d_in, const int* in_sizes, int n_in,
                              void* d_out, int out_size, void* d_ws, size_t ws_size,
                              hipStream_t stream) {
    const float* code_map = (const float*)d_in[0];
    const float* tex_map  = (const float*)d_in[1];
    const float* Wq = (const float*)d_in[2];  const float* bq = (const float*)d_in[3];
    const float* Wk = (const float*)d_in[4];  const float* bk = (const float*)d_in[5];
    const float* Wv = (const float*)d_in[6];  const float* bv = (const float*)d_in[7];
    const float* Wo = (const float*)d_in[8];  const float* bo = (const float*)d_in[9];
    const float* ln1_g = (const float*)d_in[10]; const float* ln1_b = (const float*)d_in[11];
    const float* ln2_g = (const float*)d_in[12]; const float* ln2_b = (const float*)d_in[13];
    const float* ffln_g = (const float*)d_in[14]; const float* ffln_b = (const float*)d_in[15];
    const float* W1 = (const float*)d_in[16]; const float* b1 = (const float*)d_in[17];
    const float* W2 = (const float*)d_in[18]; const float* b2 = (const float*)d_in[19];
    float* out = (float*)d_out;

    // ws layout (bf16 elements)
    bf16* ws  = (bf16*)d_ws;
    bf16* qn  = ws;                       // 4096*256 = 1048576 (pre-scaled Q)
    bf16* k4  = qn + 1048576;             // 1048576 (A-frag layout, sigma-permuted keys)
    bf16* v4  = k4 + 1048576;             // 1048576 (chunk-tiled V)
    bf16* cn  = v4 + 1048576;             // 1048576
    bf16* tn  = cn + 1048576;             // 1048576
    bf16* tb  = tn + 1048576;             // 1048576 (bf16 texture copy)
    bf16* wbf = tb + 1048576;             // 6*256*256 = 393216 (Wq,Wk,Wv,Wo,W1,W2)

    pre_kernel<<<2048 + 384, 256, 0, stream>>>(code_map, tex_map, ln1_g, ln1_b, ln2_g, ln2_b,
                                               Wq, Wk, Wv, Wo, W1, W2, cn, tn, tb, wbf);
    qkv_kernel<<<dim3(64, 4, 3), 256, 0, stream>>>(cn, tn, wbf, bq, bk, bv, qn, k4, v4);
    attn_mlp_kernel<<<dim3(64, 8), 512, 0, stream>>>(qn, k4, v4, wbf, bo, tb,
                                                     ffln_g, ffln_b, b1, b2, out);
}